// Round 3
// baseline (1479.824 us; speedup 1.0000x reference)
//
#include <hip/hip_runtime.h>

// HSMM forward, scaled linear recurrence, single-barrier scan.
// K5 fix this round: PIN the P-column in VGPRs via opaque asm (the compiler
// was rematerializing the loop-invariant P loads from L2 every step).
// ws layout (needs ~45.3 MiB):
//   H      : bf16 [16][512][11][256]  (emission*lterm, exp-domain, shift-aligned)
//   part   : f32  [11][88][256]
//   Pexp   : f32  [256][256]
//   logZ   : f32  [11][256] ; lseZ f32[256] ; lt f32[11][256] ; ltmz f32[11][256]

#define VV 50000
#define ZB 256
#define LB 11
#define BB 16
#define TB 512
#define NCHUNK 88
#define CROWS 569  // ceil(VV/NCHUNK)

static __device__ __forceinline__ float bf16u_to_f(unsigned short u) {
  return __uint_as_float(((unsigned int)u) << 16);
}
static __device__ __forceinline__ unsigned short f_to_bf16u(float f) {
  unsigned int b = __float_as_uint(f);
  b += 0x7FFFu + ((b >> 16) & 1u);
  return (unsigned short)(b >> 16);
}

// ---- K1: per-chunk sum of exp(emb) over v (no-max: emb ~ N(0,1), safe in f32)
__global__ void k1_sumexp(const float* __restrict__ emb, float* __restrict__ part) {
  const int l = blockIdx.x / NCHUNK;
  const int c = blockIdx.x % NCHUNK;
  const int t = threadIdx.x;           // 512 threads
  const int zi = (t & 63) * 4;
  const int ro = t >> 6;               // 0..7
  const int v0 = c * CROWS;
  const int v1 = (v0 + CROWS < VV) ? (v0 + CROWS) : VV;
  const float* base = emb + (size_t)l * VV * ZB;
  float a0 = 0.f, a1 = 0.f, a2 = 0.f, a3 = 0.f;
  int v = v0 + ro;
  for (; v + 24 < v1; v += 32) {
    float4 x0 = *(const float4*)(base + (size_t)(v)*ZB + zi);
    float4 x1 = *(const float4*)(base + (size_t)(v + 8) * ZB + zi);
    float4 x2 = *(const float4*)(base + (size_t)(v + 16) * ZB + zi);
    float4 x3 = *(const float4*)(base + (size_t)(v + 24) * ZB + zi);
    a0 += __expf(x0.x) + __expf(x1.x) + __expf(x2.x) + __expf(x3.x);
    a1 += __expf(x0.y) + __expf(x1.y) + __expf(x2.y) + __expf(x3.y);
    a2 += __expf(x0.z) + __expf(x1.z) + __expf(x2.z) + __expf(x3.z);
    a3 += __expf(x0.w) + __expf(x1.w) + __expf(x2.w) + __expf(x3.w);
  }
  for (; v < v1; v += 8) {
    float4 x0 = *(const float4*)(base + (size_t)v * ZB + zi);
    a0 += __expf(x0.x); a1 += __expf(x0.y); a2 += __expf(x0.z); a3 += __expf(x0.w);
  }
  __shared__ float red[8][ZB];
  red[ro][zi] = a0; red[ro][zi + 1] = a1; red[ro][zi + 2] = a2; red[ro][zi + 3] = a3;
  __syncthreads();
  if (t < ZB) {
    float s = 0.f;
#pragma unroll
    for (int r = 0; r < 8; ++r) s += red[r][t];
    part[((size_t)l * NCHUNK + c) * ZB + t] = s;
  }
}

// ---- K2: combine partials -> logZ; lse over l of l_per_z; Pexp rows
__global__ void k2_combine(const float* __restrict__ part, const float* __restrict__ zpz,
                           const float* __restrict__ lpz, float* __restrict__ logZ,
                           float* __restrict__ lseZ, float* __restrict__ Pexp) {
  const int bid = blockIdx.x;
  const int t = threadIdx.x;  // 256
  if (bid < LB) {
    float s = 0.f;
    for (int c = 0; c < NCHUNK; ++c) s += part[((size_t)bid * NCHUNK + c) * ZB + t];
    logZ[bid * ZB + t] = __logf(s);
  } else if (bid == LB) {
    float lv[LB]; float m = -1e30f;
#pragma unroll
    for (int l = 0; l < LB; ++l) { lv[l] = lpz[t * LB + l]; m = fmaxf(m, lv[l]); }
    float s = 0.f;
#pragma unroll
    for (int l = 0; l < LB; ++l) s += __expf(lv[l] - m);
    lseZ[t] = m + __logf(s);
  } else {
    const int r = bid - (LB + 1);
    const float x = zpz[r * ZB + t];
    __shared__ float sA[4], sB[4];
    float m = x;
#pragma unroll
    for (int off = 32; off >= 1; off >>= 1) m = fmaxf(m, __shfl_xor(m, off, 64));
    if ((t & 63) == 0) sA[t >> 6] = m;
    __syncthreads();
    m = fmaxf(fmaxf(sA[0], sA[1]), fmaxf(sA[2], sA[3]));
    const float e = __expf(x - m);
    float s = e;
#pragma unroll
    for (int off = 32; off >= 1; off >>= 1) s += __shfl_xor(s, off, 64);
    if ((t & 63) == 0) sB[t >> 6] = s;
    __syncthreads();
    const float tot = sB[0] + sB[1] + sB[2] + sB[3];
    Pexp[r * ZB + t] = e / tot;
  }
}

// ---- K3: small tables lt = exp(l_term), ltmz = l_term - logZ
__global__ void k3_tables(const float* __restrict__ logZ, const float* __restrict__ lseZ,
                          const float* __restrict__ lpz, float* __restrict__ lt,
                          float* __restrict__ ltmz) {
  const int l = blockIdx.x; const int z = threadIdx.x;
  const float ll = lpz[z * LB + l] - lseZ[z];
  lt[l * ZB + z] = __expf(ll);
  ltmz[l * ZB + z] = ll - logZ[l * ZB + z];
}

// ---- K4: build shift-aligned exp-domain emissions H[b][n][l][z] (bf16)
__global__ void k4_build(const int* __restrict__ ng, const float* __restrict__ emb,
                         const float* __restrict__ lt, const float* __restrict__ ltmz,
                         unsigned short* __restrict__ H) {
  const int n = blockIdx.x + 1;
  const int b = blockIdx.y;
  const int z = threadIdx.x;  // 256
  unsigned short* hrow = H + ((size_t)b * TB + n) * LB * ZB + z;
#pragma unroll
  for (int l = 0; l < LB; ++l) {
    const int s = n - 1 - l;
    float h = 0.f;
    if (s >= 0) {
      const int id = ng[((size_t)l * BB + b) * TB + s];
      if (id == 0) h = lt[l * ZB + z];
      else if (id != 1) h = __expf(emb[((size_t)l * VV + id) * ZB + z] + ltmz[l * ZB + z]);
    }
    hrow[(size_t)l * ZB] = f_to_bf16u(h);
  }
}

// ---- K5: the scan. 256 threads per block, one block per batch element.
// Single barrier per step; window + H register-resident; P-column PINNED
// in VGPRs via opaque asm (prevents LLVM's reload-rematerialization).
__global__ __launch_bounds__(256, 1)
void k5_forward(const float* __restrict__ Pexp, const unsigned short* __restrict__ H,
                const int* __restrict__ xlen, float* __restrict__ out) {
  const int b = blockIdx.x;
  const int j = threadIdx.x;  // output column / z-column owner

  __shared__ __align__(16) float S_lds[2][ZB];
  __shared__ __align__(16) float wmaxl[2][4];
  __shared__ float redm[4];
  __shared__ float red4[4];

  // P column, register resident: Pcol[z] = P[z][j]. The empty asm makes each
  // value an opaque register def -> cannot be rematerialized by reload.
  float Pcol[ZB];
#pragma unroll
  for (int z = 0; z < ZB; ++z) {
    Pcol[z] = Pexp[(size_t)z * ZB + j];
    asm volatile("" : "+v"(Pcol[z]));
  }

  // m0 = max_j P[0][j]  (P[0][j] == Pcol[0] of thread j)
  float m = Pcol[0];
#pragma unroll
  for (int off = 32; off >= 1; off >>= 1) m = fmaxf(m, __shfl_xor(m, off, 64));
  if ((j & 63) == 0) redm[j >> 6] = m;
  if (j < 4) { wmaxl[0][j] = 1.f; wmaxl[1][j] = 1.f; }
  __syncthreads();
  const float m0 = fmaxf(fmaxf(redm[0], redm[1]), fmaxf(redm[2], redm[3]));

  const int xl = xlen[b];

  // window & weights (register resident, static indexing only)
  float win[LB], wl[LB];
  win[0] = Pcol[0] / m0;
  wl[0] = 1.f;
#pragma unroll
  for (int l = 1; l < LB; ++l) { win[l] = 0.f; wl[l] = 0.f; }
  float C = __logf(m0);
  float cap = 0.f, capC = 0.f;

  // H pointer for this (b, j); prefetch step-1 emissions
  const unsigned short* hb = H + (size_t)b * TB * LB * ZB + j;
  unsigned short hc[LB];
#pragma unroll
  for (int l = 0; l < LB; ++l) hc[l] = hb[((size_t)LB + l) * ZB];

  for (int n = 1; n < TB; ++n) {
    // (pre-barrier) S[j] = sum_l wl*H*win  — all register-local
    float S = 0.f;
#pragma unroll
    for (int l = 0; l < LB; ++l) S = fmaf(wl[l] * bf16u_to_f(hc[l]), win[l], S);
    if (n == xl) { cap = S; capC = C; }
    const int pb = n & 1;
    S_lds[pb][j] = S;
    __syncthreads();

    // stale max from previous step (one broadcast b128 read)
    const float4 wm = *(const float4*)wmaxl[(n - 1) & 1];
    float mx = fmaxf(fmaxf(wm.x, wm.y), fmaxf(wm.z, wm.w));
    mx = fmaxf(mx, 1e-35f);
    const float inv = 1.0f / mx;

    // prefetch H for step n+1 (issued here, consumed before next barrier:
    // never crosses a barrier, hides under the matvec below)
    const int np = (n < TB - 1) ? n + 1 : n;
#pragma unroll
    for (int l = 0; l < LB; ++l) hc[l] = hb[((size_t)np * LB + l) * ZB];

    // scale bookkeeping (independent of matvec; interleaves with FMA issue)
    const float delta = __logf(mx);
    float mw = wl[0];
#pragma unroll
    for (int l = 1; l < LB - 1; ++l) mw = fmaxf(mw, wl[l]);
    const float a = fmaxf(delta, __logf(fmaxf(mw, 1e-37f)));
    const float es = __expf(-a);
#pragma unroll
    for (int l = LB - 1; l >= 1; --l) wl[l] = wl[l - 1] * es;
    wl[0] = __expf(delta - a);
    C += a;

    // matvec: raw[j] = sum_z S[z] * P[z][j]  (broadcast float4 reads)
    const float4* Sv = (const float4*)S_lds[pb];
    float a0 = 0.f, a1 = 0.f, a2 = 0.f, a3 = 0.f;
#pragma unroll
    for (int c = 0; c < 64; c += 4) {
      const float4 s0 = Sv[c + 0];
      const float4 s1 = Sv[c + 1];
      const float4 s2 = Sv[c + 2];
      const float4 s3 = Sv[c + 3];
      a0 = fmaf(s0.x, Pcol[4 * c + 0], a0);
      a0 = fmaf(s0.y, Pcol[4 * c + 1], a0);
      a0 = fmaf(s0.z, Pcol[4 * c + 2], a0);
      a0 = fmaf(s0.w, Pcol[4 * c + 3], a0);
      a1 = fmaf(s1.x, Pcol[4 * c + 4], a1);
      a1 = fmaf(s1.y, Pcol[4 * c + 5], a1);
      a1 = fmaf(s1.z, Pcol[4 * c + 6], a1);
      a1 = fmaf(s1.w, Pcol[4 * c + 7], a1);
      a2 = fmaf(s2.x, Pcol[4 * c + 8], a2);
      a2 = fmaf(s2.y, Pcol[4 * c + 9], a2);
      a2 = fmaf(s2.z, Pcol[4 * c + 10], a2);
      a2 = fmaf(s2.w, Pcol[4 * c + 11], a2);
      a3 = fmaf(s3.x, Pcol[4 * c + 12], a3);
      a3 = fmaf(s3.y, Pcol[4 * c + 13], a3);
      a3 = fmaf(s3.z, Pcol[4 * c + 14], a3);
      a3 = fmaf(s3.w, Pcol[4 * c + 15], a3);
    }
    const float raw = (a0 + a1) + (a2 + a3);

    // push window (static shift), scaled by stale max
#pragma unroll
    for (int l = LB - 1; l >= 1; --l) win[l] = win[l - 1];
    win[0] = raw * inv;

    // wave max of raw -> wmaxl for step n+1
    float wmv = raw;
#pragma unroll
    for (int off = 32; off >= 1; off >>= 1) wmv = fmaxf(wmv, __shfl_xor(wmv, off, 64));
    if ((j & 63) == 0) wmaxl[n & 1][j >> 6] = wmv;
  }

  // output: out[b] = capC + log(sum_j cap_j); xl==0 -> 0
  float sv = cap;
#pragma unroll
  for (int off = 32; off >= 1; off >>= 1) sv += __shfl_xor(sv, off, 64);
  if ((j & 63) == 0) red4[j >> 6] = sv;
  __syncthreads();
  if (j == 0) {
    const float tot = red4[0] + red4[1] + red4[2] + red4[3];
    out[b] = (xl == 0) ? 0.f : (__logf(tot) + capC);
  }
}

extern "C" void kernel_launch(void* const* d_in, const int* in_sizes, int n_in,
                              void* d_out, int out_size, void* d_ws, size_t ws_size,
                              hipStream_t stream) {
  (void)in_sizes; (void)n_in; (void)out_size; (void)ws_size;
  const int* xlen = (const int*)d_in[1];
  const int* ng = (const int*)d_in[2];
  const float* emb = (const float*)d_in[3];
  const float* zpz = (const float*)d_in[4];
  const float* lpz = (const float*)d_in[5];
  float* out = (float*)d_out;

  char* ws = (char*)d_ws;
  unsigned short* H = (unsigned short*)ws;
  size_t off = (size_t)BB * TB * LB * ZB * 2;
  float* part = (float*)(ws + off); off += (size_t)LB * NCHUNK * ZB * 4;
  float* Pexp = (float*)(ws + off); off += (size_t)ZB * ZB * 4;
  float* logZ = (float*)(ws + off); off += (size_t)LB * ZB * 4;
  float* lseZ = (float*)(ws + off); off += (size_t)ZB * 4;
  float* lt = (float*)(ws + off); off += (size_t)LB * ZB * 4;
  float* ltmz = (float*)(ws + off); off += (size_t)LB * ZB * 4;

  k1_sumexp<<<dim3(LB * NCHUNK), dim3(512), 0, stream>>>(emb, part);
  k2_combine<<<dim3(LB + 1 + ZB), dim3(ZB), 0, stream>>>(part, zpz, lpz, logZ, lseZ, Pexp);
  k3_tables<<<dim3(LB), dim3(ZB), 0, stream>>>(logZ, lseZ, lpz, lt, ltmz);
  k4_build<<<dim3(TB - 1, BB), dim3(ZB), 0, stream>>>(ng, emb, lt, ltmz, H);
  k5_forward<<<dim3(BB), dim3(256), 0, stream>>>(Pexp, H, xlen, out);
}

// Round 4
// 772.214 us; speedup vs baseline: 1.9163x; 1.9163x over previous
//
#include <hip/hip_runtime.h>

// HSMM forward, scaled linear recurrence.
// R4: fit P in registers for real. 512 thr/block: thread (q,j) holds HALF a
// P-column as float2[64] (128 VGPR) -> total ~210 VGPR < 256 addressable.
// Raw barriers (lgkmcnt+s_barrier, no vmcnt drain) + distance-2 H prefetch.
// ws layout (needs ~45.3 MiB): H bf16[16][512][11][256]; part f32[11][88][256];
// Pexp f32[256][256]; logZ[11][256]; lseZ[256]; lt[11][256]; ltmz[11][256].

#define VV 50000
#define ZB 256
#define LB 11
#define BB 16
#define TB 512
#define NCHUNK 88
#define CROWS 569  // ceil(VV/NCHUNK)

typedef float v2f __attribute__((ext_vector_type(2)));
typedef float v4f __attribute__((ext_vector_type(4)));

static __device__ __forceinline__ float bf16u_to_f(unsigned short u) {
  return __uint_as_float(((unsigned int)u) << 16);
}
static __device__ __forceinline__ unsigned short f_to_bf16u(float f) {
  unsigned int b = __float_as_uint(f);
  b += 0x7FFFu + ((b >> 16) & 1u);
  return (unsigned short)(b >> 16);
}
static __device__ __forceinline__ v2f fma2(v2f a, v2f b, v2f c) {
  return __builtin_elementwise_fma(a, b, c);
}

#define BAR() do { asm volatile("s_waitcnt lgkmcnt(0)" ::: "memory"); \
                   __builtin_amdgcn_s_barrier(); } while (0)

// ---- K1: per-chunk sum of exp(emb) over v (no-max: emb ~ N(0,1), safe in f32)
__global__ void k1_sumexp(const float* __restrict__ emb, float* __restrict__ part) {
  const int l = blockIdx.x / NCHUNK;
  const int c = blockIdx.x % NCHUNK;
  const int t = threadIdx.x;           // 512 threads
  const int zi = (t & 63) * 4;
  const int ro = t >> 6;               // 0..7
  const int v0 = c * CROWS;
  const int v1 = (v0 + CROWS < VV) ? (v0 + CROWS) : VV;
  const float* base = emb + (size_t)l * VV * ZB;
  float a0 = 0.f, a1 = 0.f, a2 = 0.f, a3 = 0.f;
  int v = v0 + ro;
  for (; v + 24 < v1; v += 32) {
    float4 x0 = *(const float4*)(base + (size_t)(v)*ZB + zi);
    float4 x1 = *(const float4*)(base + (size_t)(v + 8) * ZB + zi);
    float4 x2 = *(const float4*)(base + (size_t)(v + 16) * ZB + zi);
    float4 x3 = *(const float4*)(base + (size_t)(v + 24) * ZB + zi);
    a0 += __expf(x0.x) + __expf(x1.x) + __expf(x2.x) + __expf(x3.x);
    a1 += __expf(x0.y) + __expf(x1.y) + __expf(x2.y) + __expf(x3.y);
    a2 += __expf(x0.z) + __expf(x1.z) + __expf(x2.z) + __expf(x3.z);
    a3 += __expf(x0.w) + __expf(x1.w) + __expf(x2.w) + __expf(x3.w);
  }
  for (; v < v1; v += 8) {
    float4 x0 = *(const float4*)(base + (size_t)v * ZB + zi);
    a0 += __expf(x0.x); a1 += __expf(x0.y); a2 += __expf(x0.z); a3 += __expf(x0.w);
  }
  __shared__ float red[8][ZB];
  red[ro][zi] = a0; red[ro][zi + 1] = a1; red[ro][zi + 2] = a2; red[ro][zi + 3] = a3;
  __syncthreads();
  if (t < ZB) {
    float s = 0.f;
#pragma unroll
    for (int r = 0; r < 8; ++r) s += red[r][t];
    part[((size_t)l * NCHUNK + c) * ZB + t] = s;
  }
}

// ---- K2: combine partials -> logZ; lse over l of l_per_z; Pexp rows
__global__ void k2_combine(const float* __restrict__ part, const float* __restrict__ zpz,
                           const float* __restrict__ lpz, float* __restrict__ logZ,
                           float* __restrict__ lseZ, float* __restrict__ Pexp) {
  const int bid = blockIdx.x;
  const int t = threadIdx.x;  // 256
  if (bid < LB) {
    float s = 0.f;
    for (int c = 0; c < NCHUNK; ++c) s += part[((size_t)bid * NCHUNK + c) * ZB + t];
    logZ[bid * ZB + t] = __logf(s);
  } else if (bid == LB) {
    float lv[LB]; float m = -1e30f;
#pragma unroll
    for (int l = 0; l < LB; ++l) { lv[l] = lpz[t * LB + l]; m = fmaxf(m, lv[l]); }
    float s = 0.f;
#pragma unroll
    for (int l = 0; l < LB; ++l) s += __expf(lv[l] - m);
    lseZ[t] = m + __logf(s);
  } else {
    const int r = bid - (LB + 1);
    const float x = zpz[r * ZB + t];
    __shared__ float sA[4], sB[4];
    float m = x;
#pragma unroll
    for (int off = 32; off >= 1; off >>= 1) m = fmaxf(m, __shfl_xor(m, off, 64));
    if ((t & 63) == 0) sA[t >> 6] = m;
    __syncthreads();
    m = fmaxf(fmaxf(sA[0], sA[1]), fmaxf(sA[2], sA[3]));
    const float e = __expf(x - m);
    float s = e;
#pragma unroll
    for (int off = 32; off >= 1; off >>= 1) s += __shfl_xor(s, off, 64);
    if ((t & 63) == 0) sB[t >> 6] = s;
    __syncthreads();
    const float tot = sB[0] + sB[1] + sB[2] + sB[3];
    Pexp[r * ZB + t] = e / tot;
  }
}

// ---- K3: small tables lt = exp(l_term), ltmz = l_term - logZ
__global__ void k3_tables(const float* __restrict__ logZ, const float* __restrict__ lseZ,
                          const float* __restrict__ lpz, float* __restrict__ lt,
                          float* __restrict__ ltmz) {
  const int l = blockIdx.x; const int z = threadIdx.x;
  const float ll = lpz[z * LB + l] - lseZ[z];
  lt[l * ZB + z] = __expf(ll);
  ltmz[l * ZB + z] = ll - logZ[l * ZB + z];
}

// ---- K4: build shift-aligned exp-domain emissions H[b][n][l][z] (bf16)
__global__ void k4_build(const int* __restrict__ ng, const float* __restrict__ emb,
                         const float* __restrict__ lt, const float* __restrict__ ltmz,
                         unsigned short* __restrict__ H) {
  const int n = blockIdx.x + 1;
  const int b = blockIdx.y;
  const int z = threadIdx.x;  // 256
  unsigned short* hrow = H + ((size_t)b * TB + n) * LB * ZB + z;
#pragma unroll
  for (int l = 0; l < LB; ++l) {
    const int s = n - 1 - l;
    float h = 0.f;
    if (s >= 0) {
      const int id = ng[((size_t)l * BB + b) * TB + s];
      if (id == 0) h = lt[l * ZB + z];
      else if (id != 1) h = __expf(emb[((size_t)l * VV + id) * ZB + z] + ltmz[l * ZB + z]);
    }
    hrow[(size_t)l * ZB] = f_to_bf16u(h);
  }
}

// ---- K5: the scan. 512 threads/block, one block per batch element.
// thread (q = t>>8, j = t&255): owns P[z][j] for z in [q*128, q*128+128).
__global__ __launch_bounds__(512, 2)
void k5_forward(const float* __restrict__ Pexp, const unsigned short* __restrict__ H,
                const int* __restrict__ xlen, float* __restrict__ out) {
  const int b = blockIdx.x;
  const int t = threadIdx.x;
  const int q = t >> 8;
  const int j = t & 255;

  __shared__ __align__(16) float S_lds[2][ZB];
  __shared__ __align__(16) v2f part_lds[ZB];
  __shared__ __align__(16) v4f wmaxl[2];
  __shared__ float redm[4];
  __shared__ float red4[4];

  // Half P-column, packed float2, pinned in VGPRs (128 regs).
  v2f Pcol2[64];
#pragma unroll
  for (int c = 0; c < 64; ++c) {
    const int z = q * 128 + 2 * c;
    v2f p; p.x = Pexp[(size_t)z * ZB + j]; p.y = Pexp[(size_t)(z + 1) * ZB + j];
    Pcol2[c] = p;
    asm volatile("" : "+v"(Pcol2[c]));
  }

  // m0 = max_j P[0][j]
  float p0 = Pexp[j];
  float m = p0;
#pragma unroll
  for (int off = 32; off >= 1; off >>= 1) m = fmaxf(m, __shfl_xor(m, off, 64));
  if (q == 0 && (j & 63) == 0) redm[j >> 6] = m;
  if (t == 0) { v4f one = {1.f, 1.f, 1.f, 1.f}; wmaxl[0] = one; wmaxl[1] = one; }
  __syncthreads();
  const float m0 = fmaxf(fmaxf(redm[0], redm[1]), fmaxf(redm[2], redm[3]));

  const int xl = xlen[b];

  // scan state (q==0 threads only maintain these)
  float win[LB], wl[LB];
  float C = 0.f, cap = 0.f, capC = 0.f, inv = 1.f;
  unsigned short hcA[LB], hcB[LB];
  const unsigned short* hb = H + (size_t)b * TB * LB * ZB + j;

  if (q == 0) {
    win[0] = p0 / m0;
    wl[0] = 1.f;
#pragma unroll
    for (int l = 1; l < LB; ++l) { win[l] = 0.f; wl[l] = 0.f; }
    C = __logf(m0);
#pragma unroll
    for (int l = 0; l < LB; ++l) {
      hcA[l] = hb[((size_t)1 * LB + l) * ZB];
      hcB[l] = hb[((size_t)2 * LB + l) * ZB];
    }
  }

#define BODY(hbuf, n, npre)                                                    \
  do {                                                                         \
    if (q == 0) {                                                              \
      float S = 0.f;                                                           \
      _Pragma("unroll")                                                        \
      for (int l = 0; l < LB; ++l)                                             \
        S = fmaf(wl[l] * bf16u_to_f(hbuf[l]), win[l], S);                      \
      if ((n) == xl) { cap = S; capC = C; }                                    \
      S_lds[(n) & 1][j] = S;                                                   \
    }                                                                          \
    BAR();                                                                     \
    {                                                                          \
      const v4f* Sv = (const v4f*)(&S_lds[(n) & 1][q * 128]);                  \
      v2f a0 = {0.f, 0.f}, a1 = {0.f, 0.f};                                    \
      _Pragma("unroll")                                                        \
      for (int c = 0; c < 32; ++c) {                                           \
        const v4f s = Sv[c];                                                   \
        a0 = fma2(s.lo, Pcol2[2 * c], a0);                                     \
        a1 = fma2(s.hi, Pcol2[2 * c + 1], a1);                                 \
      }                                                                        \
      const v2f at = a0 + a1;                                                  \
      ((float*)&part_lds[j])[q] = at.x + at.y;                                 \
    }                                                                          \
    if (q == 0) {                                                              \
      _Pragma("unroll")                                                        \
      for (int l = 0; l < LB; ++l)                                             \
        hbuf[l] = hb[((size_t)(npre)*LB + l) * ZB];                            \
      const v4f wm = wmaxl[((n)-1) & 1];                                       \
      float mx = fmaxf(fmaxf(wm.x, wm.y), fmaxf(wm.z, wm.w));                  \
      mx = fmaxf(mx, 1e-35f);                                                  \
      inv = 1.0f / mx;                                                         \
      const float delta = __logf(mx);                                          \
      float mw = wl[0];                                                        \
      _Pragma("unroll")                                                        \
      for (int l = 1; l < LB - 1; ++l) mw = fmaxf(mw, wl[l]);                  \
      const float a = fmaxf(delta, __logf(fmaxf(mw, 1e-37f)));                 \
      const float es = __expf(-a);                                             \
      _Pragma("unroll")                                                        \
      for (int l = LB - 1; l >= 1; --l) wl[l] = wl[l - 1] * es;                \
      wl[0] = __expf(delta - a);                                               \
      C += a;                                                                  \
    }                                                                          \
    BAR();                                                                     \
    if (q == 0) {                                                              \
      const v2f pr = part_lds[j];                                              \
      const float raw = pr.x + pr.y;                                           \
      _Pragma("unroll")                                                        \
      for (int l = LB - 1; l >= 1; --l) win[l] = win[l - 1];                   \
      win[0] = raw * inv;                                                      \
      float wmv = raw;                                                         \
      _Pragma("unroll")                                                        \
      for (int off = 32; off >= 1; off >>= 1)                                  \
        wmv = fmaxf(wmv, __shfl_xor(wmv, off, 64));                            \
      if ((j & 63) == 0) ((float*)&wmaxl[(n) & 1])[j >> 6] = wmv;              \
    }                                                                          \
  } while (0)

  // xl <= 510, so steps 1..510 suffice (255 exact pairs).
  for (int n = 1; n <= 509; n += 2) {
    BODY(hcA, n, n + 2);
    const int npre2 = (n + 3 <= TB - 1) ? (n + 3) : (TB - 1);
    BODY(hcB, n + 1, npre2);
  }
#undef BODY

  // output: out[b] = capC + log(sum_j cap_j); xl==0 -> 0
  float sv = cap;
#pragma unroll
  for (int off = 32; off >= 1; off >>= 1) sv += __shfl_xor(sv, off, 64);
  if (q == 0 && (j & 63) == 0) red4[j >> 6] = sv;
  __syncthreads();
  if (t == 0) {
    const float tot = red4[0] + red4[1] + red4[2] + red4[3];
    out[b] = (xl == 0) ? 0.f : (__logf(tot) + capC);
  }
}

extern "C" void kernel_launch(void* const* d_in, const int* in_sizes, int n_in,
                              void* d_out, int out_size, void* d_ws, size_t ws_size,
                              hipStream_t stream) {
  (void)in_sizes; (void)n_in; (void)out_size; (void)ws_size;
  const int* xlen = (const int*)d_in[1];
  const int* ng = (const int*)d_in[2];
  const float* emb = (const float*)d_in[3];
  const float* zpz = (const float*)d_in[4];
  const float* lpz = (const float*)d_in[5];
  float* out = (float*)d_out;

  char* ws = (char*)d_ws;
  unsigned short* H = (unsigned short*)ws;
  size_t off = (size_t)BB * TB * LB * ZB * 2;
  float* part = (float*)(ws + off); off += (size_t)LB * NCHUNK * ZB * 4;
  float* Pexp = (float*)(ws + off); off += (size_t)ZB * ZB * 4;
  float* logZ = (float*)(ws + off); off += (size_t)LB * ZB * 4;
  float* lseZ = (float*)(ws + off); off += (size_t)ZB * 4;
  float* lt = (float*)(ws + off); off += (size_t)LB * ZB * 4;
  float* ltmz = (float*)(ws + off); off += (size_t)LB * ZB * 4;

  k1_sumexp<<<dim3(LB * NCHUNK), dim3(512), 0, stream>>>(emb, part);
  k2_combine<<<dim3(LB + 1 + ZB), dim3(ZB), 0, stream>>>(part, zpz, lpz, logZ, lseZ, Pexp);
  k3_tables<<<dim3(LB), dim3(ZB), 0, stream>>>(logZ, lseZ, lpz, lt, ltmz);
  k4_build<<<dim3(TB - 1, BB), dim3(ZB), 0, stream>>>(ng, emb, lt, ltmz, H);
  k5_forward<<<dim3(BB), dim3(512), 0, stream>>>(Pexp, H, xlen, out);
}